// Round 5
// baseline (35131.744 us; speedup 1.0000x reference)
//
#include <hip/hip_runtime.h>
#include <math.h>

// Problem dims (fixed by reference)
#define BB 32
#define SS 512
#define VV 30522
#define EE 768
#define HH 768
#define TT 9
#define G4 (4*HH)   // 3072
#define NBLK 96     // persistent LSTM grid: 96 blocks (PROVEN co-resident r1)

// ---------------------------------------------------------------------------
// Embedding gather: x[row][:] = emb[ids[row]][:]
__global__ void embed_kernel(const int* __restrict__ ids,
                             const float* __restrict__ emb,
                             float* __restrict__ x) {
    const int row = blockIdx.x;
    const int e4  = threadIdx.x;           // 0..191
    const int id  = ids[row];
    *(float4*)&x[(size_t)row * EE + e4 * 4] =
        *(const float4*)&emb[(size_t)id * EE + e4 * 4];
}

// ---------------------------------------------------------------------------
// fp32 GEMM (pure fp32 accumulate, replicating an fp32 numpy reference):
// C[M,N] = A[M,K] @ W[N,K]^T + b1[N] + b2[N]
__global__ __launch_bounds__(256) void gemm_simple(
    const float* __restrict__ A, const float* __restrict__ W,
    const float* __restrict__ bias1, const float* __restrict__ bias2,
    float* __restrict__ C, int M, int N, int K) {
    __shared__ float As[16][65];
    __shared__ float Ws[16][65];
    const int tid = threadIdx.x;
    const int tx = tid & 15, ty = tid >> 4;
    const int m0 = blockIdx.y * 64, n0 = blockIdx.x * 64;
    float acc[4][4];
    #pragma unroll
    for (int i = 0; i < 4; ++i)
        #pragma unroll
        for (int j = 0; j < 4; ++j) acc[i][j] = 0.f;

    for (int k0 = 0; k0 < K; k0 += 16) {
        #pragma unroll
        for (int i = 0; i < 4; ++i) {
            int r = ty + i * 16;            // 0..63
            As[tx][r] = A[(size_t)(m0 + r) * K + k0 + tx];
            Ws[tx][r] = W[(size_t)(n0 + r) * K + k0 + tx];
        }
        __syncthreads();
        #pragma unroll
        for (int kk = 0; kk < 16; ++kk) {
            float ar[4], br[4];
            #pragma unroll
            for (int i = 0; i < 4; ++i) ar[i] = As[kk][ty * 4 + i];
            #pragma unroll
            for (int j = 0; j < 4; ++j) br[j] = Ws[kk][tx * 4 + j];
            #pragma unroll
            for (int i = 0; i < 4; ++i)
                #pragma unroll
                for (int j = 0; j < 4; ++j) acc[i][j] += ar[i] * br[j];
        }
        __syncthreads();
    }
    #pragma unroll
    for (int i = 0; i < 4; ++i) {
        int r = m0 + ty * 4 + i;
        #pragma unroll
        for (int j = 0; j < 4; ++j) {
            int c = n0 + tx * 4 + j;
            C[(size_t)r * N + c] = acc[i][j] + bias1[c] + bias2[c];
        }
    }
}

// ---------------------------------------------------------------------------
// Zero the grid-barrier counters (must run each launch / graph replay).
__global__ void init_bars(unsigned* __restrict__ bar) {
    if (threadIdx.x < 2) bar[threadIdx.x] = 0u;
}

// ---------------------------------------------------------------------------
// Persistent full-layer LSTM, PURE fp32, one launch per layer.
// BIT-IDENTICAL math to the round-1 kernel (which passed with absmax 0.0):
// for each (u, b, gate) the dot is ONE accumulator over k = 0..767 in
// ascending order (r1 kept a0..a3 as separate chains too), and the gate
// expressions are evaluated in the same order (s + xW, same sigmoid/tanh).
// Parallelism comes from GATE-split (4 gates -> 4 waves; gates were always
// independent chains) and 4-batch float4 tiling -- NOT from k-split.
//
//   grid = 96 blocks x 256 threads (4 waves).  Block owns 8 u's.
//   Thread = (g = wave id = gate, uloc = lane>>3, bq = lane&7).
//   Per 4-k group: 1 LDS float4 (W_g[u][k..k+3], padded stride 772 ->
//   8 uloc addresses spread 4 banks apart, conflict-free, 8-way broadcast)
//   + 4 GLOBAL float4 h reads (hT[k*32 + bq*4..+3]; the wave's 8 distinct
//   float4s per k = one aligned 128 B line; L2-resident; same
//   global-read-of-hT pattern as r1's staging loop) -> 16 fmac.
//   COMPLETE per-gate sums (never partials) exchanged via a 4 KB LDS
//   buffer; owners (wave 0, 64 lanes = (uloc,bq)) hold cell state in
//   registers and apply the gate nonlinearities.
//   W reads straight from Whh (torch layout is already [g][u][k]).
//   Grid barrier: VERBATIM round-1 scheme (single monotonic device-scope
//   counter, target (t+1)*NBLK, s_sleep spin, agent release/acquire).
__global__ __launch_bounds__(256) void lstm_layer_persist(
    const float* __restrict__ xW,    // [B*S*3072] input proj + biases
    const float* __restrict__ Whh,   // [3072,768] raw torch layout
    float* __restrict__ h_out,       // [B*S*768]
    float* __restrict__ hTa,         // ping [768*32], [u*32+b]
    float* __restrict__ hTb,         // pong
    unsigned* __restrict__ bar) {    // one zeroed counter
    extern __shared__ float smem[];
    float*  wlds = smem;                     // 4*8*772 = 24704 floats (~97 KB)
    float4* red  = (float4*)(smem + 24704);  // 256 float4 = 4 KB
    const int tid  = threadIdx.x;
    const int lane = tid & 63;
    const int g    = tid >> 6;           // wave id == gate (0=i,1=f,2=g,3=o)
    const int uloc = lane >> 3;          // 0..7
    const int bq   = lane & 7;           // 0..7 (batch quad)
    const int u    = blockIdx.x * 8 + uloc;
    const bool owner = (tid < 64);       // (uloc,bq): holds c, does gates

    // one-time W stage: wlds[g][uloc][k] with +4 pad (772) for bank spread
    for (int idx = tid; idx < 6144; idx += 256) {
        const int gg  = idx / 1536;
        const int rem = idx - gg * 1536;
        const int uu  = rem / 192;
        const int k4  = rem - uu * 192;
        *(float4*)&wlds[gg * 6176 + uu * 772 + k4 * 4] =
            *(const float4*)&Whh[(size_t)(gg * 768 + blockIdx.x * 8 + uu) * 768
                                 + k4 * 4];
    }
    __syncthreads();

    const float* wrow = wlds + g * 6176 + uloc * 772;
    float cc[4] = {0.f, 0.f, 0.f, 0.f};

    for (int t = 0; t < SS; ++t) {
        // owners issue xW loads early; latency hides under the matvec
        float xg[4][4];
        if (owner) {
            #pragma unroll
            for (int j = 0; j < 4; ++j) {
                const size_t row = (size_t)(bq * 4 + j) * SS + t;
                #pragma unroll
                for (int gg = 0; gg < 4; ++gg)
                    xg[j][gg] = xW[row * G4 + gg * HH + u];
            }
        }

        if (t > 0) {
            const float4* hp = (const float4*)((t & 1) ? hTb : hTa);
            float4 s = {0.f, 0.f, 0.f, 0.f};   // gate g, batches bq*4..+3
            #pragma unroll 4
            for (int k4 = 0; k4 < 192; ++k4) {
                const float4 w4 = *(const float4*)&wrow[k4 * 4];
                const float4 h0 = hp[(k4 * 4 + 0) * 8 + bq];
                const float4 h1 = hp[(k4 * 4 + 1) * 8 + bq];
                const float4 h2 = hp[(k4 * 4 + 2) * 8 + bq];
                const float4 h3 = hp[(k4 * 4 + 3) * 8 + bq];
                // k ascending per accumulator component -> r1's exact chain
                s.x += w4.x * h0.x; s.y += w4.x * h0.y; s.z += w4.x * h0.z; s.w += w4.x * h0.w;
                s.x += w4.y * h1.x; s.y += w4.y * h1.y; s.z += w4.y * h1.z; s.w += w4.y * h1.w;
                s.x += w4.z * h2.x; s.y += w4.z * h2.y; s.z += w4.z * h2.z; s.w += w4.z * h2.w;
                s.x += w4.w * h3.x; s.y += w4.w * h3.y; s.z += w4.w * h3.z; s.w += w4.w * h3.w;
            }
            red[g * 64 + lane] = s;          // complete sum, no partials
        }
        __syncthreads();                     // red visible to owners

        if (owner) {
            float si_[4], sf_[4], sk_[4], so_[4];
            if (t > 0) {
                const float4 s0 = red[0 * 64 + lane];
                const float4 s1 = red[1 * 64 + lane];
                const float4 s2 = red[2 * 64 + lane];
                const float4 s3 = red[3 * 64 + lane];
                si_[0]=s0.x; si_[1]=s0.y; si_[2]=s0.z; si_[3]=s0.w;
                sf_[0]=s1.x; sf_[1]=s1.y; sf_[2]=s1.z; sf_[3]=s1.w;
                sk_[0]=s2.x; sk_[1]=s2.y; sk_[2]=s2.z; sk_[3]=s2.w;
                so_[0]=s3.x; so_[1]=s3.y; so_[2]=s3.z; so_[3]=s3.w;
            } else {
                #pragma unroll
                for (int j = 0; j < 4; ++j)
                    si_[j] = sf_[j] = sk_[j] = so_[j] = 0.f;
            }
            float* hTo = (t & 1) ? hTa : hTb;   // step t writes hbuf[(t+1)&1]
            float hvv[4];
            #pragma unroll
            for (int j = 0; j < 4; ++j) {
                const float gi = si_[j] + xg[j][0];   // same order as r1: a0 + xW
                const float gf = sf_[j] + xg[j][1];
                const float gg = sk_[j] + xg[j][2];
                const float go = so_[j] + xg[j][3];
                const float sI = 1.f / (1.f + expf(-gi));
                const float sF = 1.f / (1.f + expf(-gf));
                const float sO = 1.f / (1.f + expf(-go));
                const float tG = tanhf(gg);
                cc[j] = sF * cc[j] + sI * tG;
                const float h = sO * tanhf(cc[j]);
                hvv[j] = h;
                h_out[((size_t)(bq * 4 + j) * SS + t) * HH + u] = h;
            }
            *(float4*)&hTo[u * 32 + bq * 4] =
                make_float4(hvv[0], hvv[1], hvv[2], hvv[3]);
        }

        if (t < SS - 1) {
            // grid barrier: all blocks must finish step t before t+1
            __syncthreads();                 // drains this block's stores
            if (tid == 0) {
                __builtin_amdgcn_fence(__ATOMIC_RELEASE, "agent");
                atomicAdd(bar, 1u);          // device scope by default
                const unsigned target = (unsigned)(t + 1) * NBLK;
                while (__hip_atomic_load(bar, __ATOMIC_RELAXED,
                                         __HIP_MEMORY_SCOPE_AGENT) < target)
                    __builtin_amdgcn_s_sleep(1);
                __builtin_amdgcn_fence(__ATOMIC_ACQUIRE, "agent");
            }
            __syncthreads();
        }
    }
}

// ---------------------------------------------------------------------------
// Scalar logits + log_softmax, pure fp32, one thread per row.
__global__ __launch_bounds__(256) void logits_kernel(
    const float* __restrict__ h, const float* __restrict__ Wout,
    const float* __restrict__ bout, float* __restrict__ logp) {
    const int row = blockIdx.x * 256 + threadIdx.x;   // 0..16383
    const float* hr = &h[(size_t)row * HH];
    float lg[TT];
    for (int tt = 0; tt < TT; ++tt) {
        const float* wr = &Wout[tt * HH];
        float ps = 0.f;
        for (int k = 0; k < HH; ++k) ps += hr[k] * wr[k];
        lg[tt] = ps + bout[tt];
    }
    float mx = lg[0];
    for (int tt = 1; tt < TT; ++tt) mx = fmaxf(mx, lg[tt]);
    float sm = 0.f;
    for (int tt = 0; tt < TT; ++tt) sm += expf(lg[tt] - mx);
    float lse = mx + logf(sm);
    for (int tt = 0; tt < TT; ++tt) logp[(size_t)row * TT + tt] = lg[tt] - lse;
}

// ---------------------------------------------------------------------------
// CRF forward (loss), pure fp32: wave per batch, lanes = next-tag. 32 blocks.
#define NEG_INF_F -3.0e38f
__global__ __launch_bounds__(64) void crf_forward(
    const float* __restrict__ logp, const int* __restrict__ labels,
    const int* __restrict__ mask, const float* __restrict__ start_t,
    const float* __restrict__ end_t, const float* __restrict__ trans,
    float* __restrict__ bstats) {
    const int b = blockIdx.x;
    const int lane = threadIdx.x;
    const int j = lane < TT ? lane : TT - 1;
    const float* em = logp + (size_t)b * SS * TT;
    const int* mk = mask + b * SS;
    const int* lb = labels + b * SS;
    float tr[TT];
    #pragma unroll
    for (int i = 0; i < TT; ++i) tr[i] = trans[i * TT + j];
    float sc = start_t[j] + em[j];

    for (int t = 1; t < SS; ++t) {
        const int m = mk[t];
        const float e = em[t * TT + j];
        float v[TT];
        #pragma unroll
        for (int i = 0; i < TT; ++i) v[i] = __shfl(sc, i) + tr[i];
        float mx = v[0];
        #pragma unroll
        for (int i = 1; i < TT; ++i) mx = fmaxf(mx, v[i]);
        float smv = 0.f;
        #pragma unroll
        for (int i = 0; i < TT; ++i) smv += expf(v[i] - mx);
        float nxt = mx + logf(smv) + e;
        sc = m ? nxt : sc;
    }
    float fin = sc + end_t[j];
    float fv[TT];
    #pragma unroll
    for (int i = 0; i < TT; ++i) fv[i] = __shfl(fin, i);
    float mx = fv[0];
    #pragma unroll
    for (int i = 1; i < TT; ++i) mx = fmaxf(mx, fv[i]);
    float smv = 0.f;
    #pragma unroll
    for (int i = 0; i < TT; ++i) smv += expf(fv[i] - mx);
    float denom = mx + logf(smv);
    // numerator + token count
    float np = 0.f; int ic = 0;
    for (int t = lane; t < SS; t += 64) {
        int m = mk[t];
        ic += m;
        if (t > 0 && m) {
            int tg = lb[t], tp = lb[t - 1];
            np += trans[tp * TT + tg] + em[t * TT + tg];
        }
    }
    for (int off = 32; off; off >>= 1) {
        np += __shfl_down(np, off);
        ic += __shfl_down(ic, off);
    }
    if (lane == 0) {
        int tg0 = lb[0];
        np += start_t[tg0] + em[tg0];
        int tgl = lb[ic - 1];              // mask is a contiguous prefix
        np += end_t[tgl];
        bstats[b * 3 + 0] = np;
        bstats[b * 3 + 1] = denom;
        bstats[b * 3 + 2] = (float)ic;
    }
}

// ---------------------------------------------------------------------------
// Fully scalar Viterbi decode, pure fp32: one thread per batch.
__global__ __launch_bounds__(64) void crf_decode(
    const float* __restrict__ logp, const int* __restrict__ mask,
    const float* __restrict__ start_t, const float* __restrict__ end_t,
    const float* __restrict__ trans, float* __restrict__ preds) {
    __shared__ unsigned char bp[SS][TT];
    if (threadIdx.x != 0) return;
    const int b = blockIdx.x;
    const float* em = logp + (size_t)b * SS * TT;
    const int* mk = mask + b * SS;
    float sc[TT], nx[TT];
    for (int jj = 0; jj < TT; ++jj) sc[jj] = start_t[jj] + em[jj];

    for (int t = 1; t < SS; ++t) {
        const int m = mk[t];
        for (int jj = 0; jj < TT; ++jj) {
            float bmv = NEG_INF_F; int bi = 0;
            for (int i = 0; i < TT; ++i) {
                float v = sc[i] + trans[i * TT + jj];
                if (v > bmv) { bmv = v; bi = i; }     // first max wins
            }
            nx[jj] = bmv + em[t * TT + jj];
            bp[t][jj] = (unsigned char)(m ? bi : jj); // identity when masked
        }
        if (m) for (int jj = 0; jj < TT; ++jj) sc[jj] = nx[jj];
    }
    float bm = NEG_INF_F; int best = 0;
    for (int jj = 0; jj < TT; ++jj) {
        float v = sc[jj] + end_t[jj];
        if (v > bm) { bm = v; best = jj; }
    }
    int tag = best;
    preds[b * SS + (SS - 1)] = (float)(mk[SS - 1] ? tag : 0);
    for (int t = SS - 1; t >= 1; --t) {
        tag = bp[t][tag];
        preds[b * SS + t - 1] = (float)(mk[t - 1] ? tag : 0);
    }
}

__global__ void loss_kernel(const float* __restrict__ bstats,
                            float* __restrict__ out) {
    const int lane = threadIdx.x;
    float nd = 0.f, c = 0.f;
    if (lane < 32) {
        nd = bstats[lane * 3] - bstats[lane * 3 + 1];
        c  = bstats[lane * 3 + 2];
    }
    for (int off = 32; off; off >>= 1) {
        nd += __shfl_down(nd, off);
        c  += __shfl_down(c, off);
    }
    if (lane == 0) out[0] = -nd / c;
}

// ---------------------------------------------------------------------------
extern "C" void kernel_launch(void* const* d_in, const int* in_sizes, int n_in,
                              void* d_out, int out_size, void* d_ws, size_t ws_size,
                              hipStream_t stream) {
    const int*   ids   = (const int*)d_in[0];
    const int*   amask = (const int*)d_in[1];
    const int*   labels= (const int*)d_in[2];
    const float* emb   = (const float*)d_in[3];
    const float* Wih0  = (const float*)d_in[4];
    const float* Whh0  = (const float*)d_in[5];
    const float* bih0  = (const float*)d_in[6];
    const float* bhh0  = (const float*)d_in[7];
    const float* Wih1  = (const float*)d_in[8];
    const float* Whh1  = (const float*)d_in[9];
    const float* bih1  = (const float*)d_in[10];
    const float* bhh1  = (const float*)d_in[11];
    const float* Wout  = (const float*)d_in[12];
    const float* boutp = (const float*)d_in[13];
    const float* st    = (const float*)d_in[14];
    const float* et    = (const float*)d_in[15];
    const float* trp   = (const float*)d_in[16];

    // workspace layout (floats). Same known-good footprint as round 1;
    // wpk region is now unused (W reads straight from Whh) but kept so the
    // cbuf/barrier offsets stay identical.
    float* ws     = (float*)d_ws;
    float* slab   = ws;                       // 12,582,912 (x / h0 / h1)
    float* xW     = slab + 12582912;          // 50,331,648 (gate pre-acts)
    float* hTa    = xW + 50331648;            // 24,576 (ping)
    float* hTb    = hTa + 24576;              // 24,576 (pong)
    float* wpk    = hTb + 24576;              // 2,359,296 (unused)
    float* cb     = wpk + 2359296;            // 24,576 (barrier counters)
    float* logp   = cb + 24576;               // 147,456
    float* bstats = logp + 147456;            // 96
    unsigned* bar = (unsigned*)cb;
    float* out    = (float*)d_out;
    (void)wpk;

    // allow ~101 KB dynamic LDS for the persistent kernel (1 block/CU)
    static bool attr_done = false;
    if (!attr_done) {
        hipFuncSetAttribute((const void*)lstm_layer_persist,
                            hipFuncAttributeMaxDynamicSharedMemorySize,
                            102912);
        attr_done = true;
    }

    dim3 ggrid(G4 / 64, (BB * SS) / 64);      // (48, 256)

    init_bars<<<1, 64, 0, stream>>>(bar);

    // layer 0
    embed_kernel<<<BB * SS, EE / 4, 0, stream>>>(ids, emb, slab);
    gemm_simple<<<ggrid, 256, 0, stream>>>(slab, Wih0, bih0, bhh0, xW,
                                           BB * SS, G4, EE);
    lstm_layer_persist<<<NBLK, 256, 102912, stream>>>(xW, Whh0, slab,
                                                      hTa, hTb, bar + 0);

    // layer 1
    gemm_simple<<<ggrid, 256, 0, stream>>>(slab, Wih1, bih1, bhh1, xW,
                                           BB * SS, G4, HH);
    lstm_layer_persist<<<NBLK, 256, 102912, stream>>>(xW, Whh1, slab,
                                                      hTa, hTb, bar + 1);

    // projection + log_softmax (scalar fp32)
    logits_kernel<<<(BB * SS) / 256, 256, 0, stream>>>(slab, Wout, boutp, logp);

    // CRF loss + scalar decode (fp32)
    crf_forward<<<32, 64, 0, stream>>>(logp, labels, amask, st, et, trp, bstats);
    crf_decode<<<32, 64, 0, stream>>>(logp, amask, st, et, trp, out + 1);
    loss_kernel<<<1, 64, 0, stream>>>(bstats, out);
}